// Round 4
// baseline (186.587 us; speedup 1.0000x reference)
//
#include <hip/hip_runtime.h>

#define MARGIN 0.2472f
#define SENT_NUM 16384
#define ANN_NUM 8192
#define RPB 8                      // rows per block
#define NBLK (SENT_NUM / RPB)      // 2048 blocks

typedef float f32x4 __attribute__((ext_vector_type(4)));  // clang vector: OK for nontemporal builtin

// Fused single kernel: each block hinge-sums 8 consecutive rows (256 KiB,
// nontemporal float4 streams), writes one partial, and the last block to
// finish reduces all partials and writes the scalar (last-block-done
// pattern; atomic order never feeds arithmetic, so output is deterministic).
// The j==pann term contributes exactly MARGIN, so we sum all j and subtract
// SENT_NUM*MARGIN at the end.
__global__ __launch_bounds__(256) void hinge_fused_kernel(
        const float* __restrict__ att,
        const int* __restrict__ pann,
        float* __restrict__ partials,
        unsigned int* __restrict__ counter,
        float* __restrict__ out) {
    const int b = blockIdx.x;
    const int t = threadIdx.x;
    const int row0 = b * RPB;

    __shared__ float s_th[RPB];
    if (t < RPB)
        s_th[t] = MARGIN - att[(size_t)(row0 + t) * ANN_NUM + pann[row0 + t]];
    __syncthreads();

    const f32x4* base4 = (const f32x4*)(att + (size_t)row0 * ANN_NUM);
    float acc0 = 0.0f, acc1 = 0.0f;
    // 8 rows x 2048 float4; 256 threads -> 8 float4/thread/row, stride 256
    #pragma unroll 2
    for (int r = 0; r < RPB; ++r) {
        const f32x4* rp4 = base4 + (size_t)r * (ANN_NUM / 4);
        const float th = s_th[r];
        #pragma unroll
        for (int k = 0; k < 8; k += 2) {
            f32x4 v0 = __builtin_nontemporal_load(&rp4[t + k * 256]);
            f32x4 v1 = __builtin_nontemporal_load(&rp4[t + (k + 1) * 256]);
            acc0 += fmaxf(v0.x + th, 0.0f) + fmaxf(v0.y + th, 0.0f)
                  + fmaxf(v0.z + th, 0.0f) + fmaxf(v0.w + th, 0.0f);
            acc1 += fmaxf(v1.x + th, 0.0f) + fmaxf(v1.y + th, 0.0f)
                  + fmaxf(v1.z + th, 0.0f) + fmaxf(v1.w + th, 0.0f);
        }
    }
    float acc = acc0 + acc1;

    // wave64 shuffle reduce, then cross-wave via LDS
    #pragma unroll
    for (int off = 32; off > 0; off >>= 1)
        acc += __shfl_down(acc, off, 64);

    __shared__ float wsum[4];
    if ((t & 63) == 0) wsum[t >> 6] = acc;
    __syncthreads();

    __shared__ bool s_last;
    if (t == 0) {
        partials[b] = wsum[0] + wsum[1] + wsum[2] + wsum[3];
        __threadfence();                               // release partial
        unsigned int prev = atomicAdd(counter, 1u);    // device-scope
        s_last = (prev == NBLK - 1);
    }
    __syncthreads();
    if (!s_last) return;

    // ---- last block: final reduction over NBLK partials ----
    __threadfence();                                   // acquire all partials
    double dacc = 0.0;
    #pragma unroll
    for (int i = 0; i < NBLK / 256; ++i)
        dacc += (double)partials[t + i * 256];

    #pragma unroll
    for (int off = 32; off > 0; off >>= 1)
        dacc += __shfl_down(dacc, off, 64);

    __shared__ double dsum[4];
    if ((t & 63) == 0) dsum[t >> 6] = dacc;
    __syncthreads();
    if (t == 0) {
        double total = dsum[0] + dsum[1] + dsum[2] + dsum[3];
        total -= (double)SENT_NUM * (double)MARGIN;    // remove j==pann terms
        out[0] = (float)(total / ((double)SENT_NUM * (double)ANN_NUM));
    }
}

extern "C" void kernel_launch(void* const* d_in, const int* in_sizes, int n_in,
                              void* d_out, int out_size, void* d_ws, size_t ws_size,
                              hipStream_t stream) {
    const float* att  = (const float*)d_in[0];
    const int*   pann = (const int*)d_in[1];
    float* out = (float*)d_out;

    // d_ws layout: [0,4)   counter (must start 0 each call)
    //              [256, ) NBLK float partials
    unsigned int* counter  = (unsigned int*)d_ws;
    float*        partials = (float*)((char*)d_ws + 256);

    (void)hipMemsetAsync(counter, 0, sizeof(unsigned int), stream);
    hinge_fused_kernel<<<NBLK, 256, 0, stream>>>(att, pann, partials, counter, out);
}

// Round 5
// 95.297 us; speedup vs baseline: 1.9580x; 1.9580x over previous
//
#include <hip/hip_runtime.h>

#define MARGIN 0.2472f
#define SENT_NUM 16384
#define ANN_NUM 8192
#define RPB 16                     // rows per block
#define NBLK (SENT_NUM / RPB)      // 1024 blocks = 4 per CU exactly

// Each block handles 16 consecutive rows (512 KiB contiguous). pos thresholds
// for the 16 rows are gathered once into LDS, then the block streams the rows
// with float4 coalesced loads (two independent accumulator chains for ILP).
// The j==pann term contributes exactly MARGIN (att[i,pann]-pos == 0 in fp),
// so we sum over all j and subtract SENT_NUM*MARGIN at the end.
__global__ __launch_bounds__(256) void hinge_rows_kernel(
        const float* __restrict__ att,
        const int* __restrict__ pann,
        float* __restrict__ partials) {
    const int b = blockIdx.x;
    const int t = threadIdx.x;
    const int row0 = b * RPB;

    __shared__ float s_th[RPB];
    if (t < RPB)
        s_th[t] = MARGIN - att[(size_t)(row0 + t) * ANN_NUM + pann[row0 + t]];
    __syncthreads();

    const float4* base4 = (const float4*)(att + (size_t)row0 * ANN_NUM);
    float acc0 = 0.0f, acc1 = 0.0f;
    // 16 rows x 2048 float4; 256 threads -> 8 float4/thread/row, stride 256
    #pragma unroll 2
    for (int r = 0; r < RPB; ++r) {
        const float4* rp4 = base4 + (size_t)r * (ANN_NUM / 4);
        const float th = s_th[r];
        #pragma unroll
        for (int k = 0; k < 8; k += 2) {
            float4 v0 = rp4[t + k * 256];
            float4 v1 = rp4[t + (k + 1) * 256];
            acc0 += fmaxf(v0.x + th, 0.0f) + fmaxf(v0.y + th, 0.0f)
                  + fmaxf(v0.z + th, 0.0f) + fmaxf(v0.w + th, 0.0f);
            acc1 += fmaxf(v1.x + th, 0.0f) + fmaxf(v1.y + th, 0.0f)
                  + fmaxf(v1.z + th, 0.0f) + fmaxf(v1.w + th, 0.0f);
        }
    }
    float acc = acc0 + acc1;

    // wave64 shuffle reduce, then cross-wave via LDS
    #pragma unroll
    for (int off = 32; off > 0; off >>= 1)
        acc += __shfl_down(acc, off, 64);

    __shared__ float wsum[4];
    if ((t & 63) == 0) wsum[t >> 6] = acc;
    __syncthreads();
    if (t == 0)
        partials[b] = wsum[0] + wsum[1] + wsum[2] + wsum[3];
}

__global__ __launch_bounds__(256) void reduce_final_kernel(
        const float* __restrict__ partials,
        float* __restrict__ out) {
    double acc = 0.0;
    #pragma unroll
    for (int i = 0; i < NBLK / 256; ++i)
        acc += (double)partials[threadIdx.x + i * 256];

    #pragma unroll
    for (int off = 32; off > 0; off >>= 1)
        acc += __shfl_down(acc, off, 64);

    __shared__ double wsum[4];
    if ((threadIdx.x & 63) == 0) wsum[threadIdx.x >> 6] = acc;
    __syncthreads();
    if (threadIdx.x == 0) {
        double total = wsum[0] + wsum[1] + wsum[2] + wsum[3];
        total -= (double)SENT_NUM * (double)MARGIN;   // remove the j==pann terms
        out[0] = (float)(total / ((double)SENT_NUM * (double)ANN_NUM));
    }
}

extern "C" void kernel_launch(void* const* d_in, const int* in_sizes, int n_in,
                              void* d_out, int out_size, void* d_ws, size_t ws_size,
                              hipStream_t stream) {
    const float* att  = (const float*)d_in[0];
    const int*   pann = (const int*)d_in[1];
    float* out      = (float*)d_out;
    float* partials = (float*)d_ws;   // NBLK floats = 4 KiB

    hinge_rows_kernel<<<NBLK, 256, 0, stream>>>(att, pann, partials);
    reduce_final_kernel<<<1, 256, 0, stream>>>(partials, out);
}

// Round 6
// 94.287 us; speedup vs baseline: 1.9789x; 1.0107x over previous
//
#include <hip/hip_runtime.h>

#define MARGIN 0.2472f
#define SENT_NUM 16384
#define ANN_NUM 8192
#define RPB 16                     // rows per block
#define NBLK (SENT_NUM / RPB)      // 1024 blocks = 4 per CU exactly

// Each block handles 16 INTERLEAVED rows: block b owns rows {b, b+NBLK, ...}.
// During sub-row iteration j the whole grid sweeps a contiguous 32 MiB window
// (rows j*NBLK .. j*NBLK+1023) — fill-like moving-window access for DRAM
// row-buffer locality, instead of 1024 scattered stream heads.
// pos thresholds for the 16 rows are gathered once into LDS, then the block
// streams the rows with float4 coalesced loads (two accumulator chains).
// The j==pann term contributes exactly MARGIN (att[i,pann]-pos == 0 in fp),
// so we sum over all j and subtract SENT_NUM*MARGIN at the end.
__global__ __launch_bounds__(256) void hinge_rows_kernel(
        const float* __restrict__ att,
        const int* __restrict__ pann,
        float* __restrict__ partials) {
    const int b = blockIdx.x;
    const int t = threadIdx.x;

    __shared__ float s_th[RPB];
    if (t < RPB) {
        const int row = b + t * NBLK;
        s_th[t] = MARGIN - att[(size_t)row * ANN_NUM + pann[row]];
    }
    __syncthreads();

    float acc0 = 0.0f, acc1 = 0.0f;
    // 16 rows x 2048 float4; 256 threads -> 8 float4/thread/row, stride 256
    #pragma unroll 2
    for (int r = 0; r < RPB; ++r) {
        const int row = b + r * NBLK;
        const float4* rp4 = (const float4*)(att + (size_t)row * ANN_NUM);
        const float th = s_th[r];
        #pragma unroll
        for (int k = 0; k < 8; k += 2) {
            float4 v0 = rp4[t + k * 256];
            float4 v1 = rp4[t + (k + 1) * 256];
            acc0 += fmaxf(v0.x + th, 0.0f) + fmaxf(v0.y + th, 0.0f)
                  + fmaxf(v0.z + th, 0.0f) + fmaxf(v0.w + th, 0.0f);
            acc1 += fmaxf(v1.x + th, 0.0f) + fmaxf(v1.y + th, 0.0f)
                  + fmaxf(v1.z + th, 0.0f) + fmaxf(v1.w + th, 0.0f);
        }
    }
    float acc = acc0 + acc1;

    // wave64 shuffle reduce, then cross-wave via LDS
    #pragma unroll
    for (int off = 32; off > 0; off >>= 1)
        acc += __shfl_down(acc, off, 64);

    __shared__ float wsum[4];
    if ((t & 63) == 0) wsum[t >> 6] = acc;
    __syncthreads();
    if (t == 0)
        partials[b] = wsum[0] + wsum[1] + wsum[2] + wsum[3];
}

__global__ __launch_bounds__(256) void reduce_final_kernel(
        const float* __restrict__ partials,
        float* __restrict__ out) {
    double acc = 0.0;
    #pragma unroll
    for (int i = 0; i < NBLK / 256; ++i)
        acc += (double)partials[threadIdx.x + i * 256];

    #pragma unroll
    for (int off = 32; off > 0; off >>= 1)
        acc += __shfl_down(acc, off, 64);

    __shared__ double wsum[4];
    if ((threadIdx.x & 63) == 0) wsum[threadIdx.x >> 6] = acc;
    __syncthreads();
    if (threadIdx.x == 0) {
        double total = wsum[0] + wsum[1] + wsum[2] + wsum[3];
        total -= (double)SENT_NUM * (double)MARGIN;   // remove the j==pann terms
        out[0] = (float)(total / ((double)SENT_NUM * (double)ANN_NUM));
    }
}

extern "C" void kernel_launch(void* const* d_in, const int* in_sizes, int n_in,
                              void* d_out, int out_size, void* d_ws, size_t ws_size,
                              hipStream_t stream) {
    const float* att  = (const float*)d_in[0];
    const int*   pann = (const int*)d_in[1];
    float* out      = (float*)d_out;
    float* partials = (float*)d_ws;   // NBLK floats = 4 KiB

    hinge_rows_kernel<<<NBLK, 256, 0, stream>>>(att, pann, partials);
    reduce_final_kernel<<<1, 256, 0, stream>>>(partials, out);
}